// Round 3
// baseline (109.790 us; speedup 1.0000x reference)
//
#include <hip/hip_runtime.h>
#include <hip/hip_bf16.h>

#define BATCH 65536
#define IN    64
#define H     128
#define NA    16
#define NBLK  256      // 1 block per CU, 155 KB LDS
#define TPB   512      // 8 waves; each wave owns 32 batch rows (2 column-sets)

typedef __bf16 bf16x8 __attribute__((ext_vector_type(8)));
typedef float  f32x4  __attribute__((ext_vector_type(4)));

union Frag { uint4 u; bf16x8 v; };
struct F32x8 { float4 a, b; };

#define EXP2F(v) __builtin_amdgcn_exp2f(v)
#define RCPF(v)  __builtin_amdgcn_rcpf(v)
#define K1 1.442695041f   // log2(e)
#define K2 2.885390082f   // 2*log2(e)

__device__ __forceinline__ F32x8 ld8f(const float* p) {
    F32x8 r;
    r.a = *reinterpret_cast<const float4*>(p);
    r.b = *reinterpret_cast<const float4*>(p + 4);
    return r;
}
__device__ __forceinline__ Frag cvt8(F32x8 x) {
    Frag f;
    f.v[0]=(__bf16)x.a.x; f.v[1]=(__bf16)x.a.y; f.v[2]=(__bf16)x.a.z; f.v[3]=(__bf16)x.a.w;
    f.v[4]=(__bf16)x.b.x; f.v[5]=(__bf16)x.b.y; f.v[6]=(__bf16)x.b.z; f.v[7]=(__bf16)x.b.w;
    return f;
}
__device__ __forceinline__ Frag cvt44(float4 a, float4 b) {
    Frag f;
    f.v[0]=(__bf16)a.x; f.v[1]=(__bf16)a.y; f.v[2]=(__bf16)a.z; f.v[3]=(__bf16)a.w;
    f.v[4]=(__bf16)b.x; f.v[5]=(__bf16)b.y; f.v[6]=(__bf16)b.z; f.v[7]=(__bf16)b.w;
    return f;
}
__device__ __forceinline__ unsigned pk2(float lo, float hi) {
    unsigned short l = __builtin_bit_cast(unsigned short, (__bf16)lo);
    unsigned short h = __builtin_bit_cast(unsigned short, (__bf16)hi);
    return (unsigned)l | ((unsigned)h << 16);
}
__device__ __forceinline__ float clamp30(float v) {
    return __builtin_fminf(__builtin_fmaxf(v, -30.0f), 30.0f);
}
// h = sigmoid(o)*tanh(sigmoid(i)*tanh(g)); f-gate dead (c_prev=0).
__device__ __forceinline__ float lstm_h(float ip, float gp, float op) {
    ip = clamp30(ip); gp = clamp30(gp); op = clamp30(op);
    const float Ei = EXP2F(-K1 * ip);
    const float Eg = EXP2F( K2 * gp);
    const float c2 = (Eg - 1.0f) * RCPF((1.0f + Ei) * (Eg + 1.0f));
    const float Eo = EXP2F(-K1 * op);
    const float Ec = EXP2F( K2 * c2);
    return (Ec - 1.0f) * RCPF((1.0f + Eo) * (Ec + 1.0f));
}

// ===========================================================================
// R3: code-size attack (I-cache theory). R1/R2 fully-unrolled body was
// ~4.5K instrs (~35-45 KB) vs 32 KB I$ -> every wave streams the whole
// kernel from L2 exactly once; explains the ~50% idle insensitive to
// occupancy/LDS (R2 null result). Changes vs R2 (math/layouts identical):
//  - hw0[] register array eliminated: layer-0 (static unroll) writes packed
//    h-words DIRECTLY into b1[2][4] frag components (static .x/.y/.z/.w).
//  - layer-1 + heads fused into ONE '#pragma unroll 1' runtime loop over the
//    8 output chunks; all register indices static inside (rule #20 safe);
//    hw1[] eliminated via uint2 hold + immediate head-MFMA on odd chunks.
//  -> ~15 KB code, fits I$.
// MFMA layouts: A: M-row=lane&15, k=quad*8+j. B: N-col=lane&15, k=quad*8+j.
//               D: N-col=lane&15, M-row=quad*4+reg.
// pi-trick: next layer's B-frag for k-tile kt := packed h-words {w[4kt+j2]};
// Wih1/Wp columns stored permuted by the same bijection pi at staging time ->
// no shuffles / LDS round-trips / barriers between layers.
// Staging granule (row n, slot s; kt=s>>2, qq=s&3) = [W[n][32kt+4qq..+3],
// W[n][32kt+16+4qq..+3]].  Slot XOR-swizzle (s ^ (n&7)) -> 2-way reads (free).
// ===========================================================================
__global__ __launch_bounds__(TPB, 2)
void lstm_fused(const float* __restrict__ x,
                const float* __restrict__ Wih0,
                const float* __restrict__ bih0,
                const float* __restrict__ bhh0,
                const float* __restrict__ Wih1,
                const float* __restrict__ bih1,
                const float* __restrict__ bhh1,
                const float* __restrict__ Wp,
                const float* __restrict__ bp,
                const float* __restrict__ Wv,
                const float* __restrict__ bv,
                float* __restrict__ out)
{
    __shared__ __align__(16) uint4 w0s[384 * 8];   // 48 KB  Wih0 igo, linear k
    __shared__ __align__(16) uint4 w1s[384 * 16];  // 96 KB  Wih1 igo, pi-permuted k
    __shared__ __align__(16) uint4 wph[32 * 16];   //  8 KB  rows 0-15 Wp, 16 Wv, 17-31 zero
    __shared__ float b0s[384];                     // bih0+bhh0, igo-packed
    __shared__ float b1s[384];                     // bih1+bhh1

    const int tid  = threadIdx.x;
    const int wave = tid >> 6;
    const int lane = tid & 63;
    const int q    = lane >> 4;
    const int m    = lane & 15;
    const int rbase = blockIdx.x * 256 + wave * 32;      // 32 rows per wave
    const f32x4 vzero = {0.f, 0.f, 0.f, 0.f};

    // ---- x prefetch (HBM, longest latency) issued before weight staging ----
    F32x8 xr[2][2];
#pragma unroll
    for (int s2 = 0; s2 < 2; ++s2) {
        const float* xp = x + (size_t)(rbase + s2 * 16 + m) * IN + q * 8;
        xr[s2][0] = ld8f(xp);
        xr[s2][1] = ld8f(xp + 32);
    }
    const float4 bpr = *reinterpret_cast<const float4*>(bp + q * 4);
    const float  bvv = bv[0];

    // ---- Stage Wih0: 3072 granules (row j = g*128+h, 8 slots of 8 cols) ----
#pragma unroll
    for (int r = 0; r < 6; ++r) {
        const int idx = tid + (r << 9);
        const int j = idx >> 3, s = idx & 7;
        const int g = j >> 7, h = j & 127;
        const int srow = h + ((g == 0) ? 0 : (g + 1) * 128);   // i,g,o -> 0,2H,3H
        Frag f = cvt8(ld8f(Wih0 + (size_t)srow * IN + s * 8));
        w0s[(j << 3) + (s ^ (j & 7))] = f.u;
    }
    // ---- Stage Wih1 pi-permuted: 6144 granules (16 slots per row) ----
#pragma unroll
    for (int r = 0; r < 12; ++r) {
        const int idx = tid + (r << 9);
        const int j = idx >> 4, s = idx & 15;
        const int g = j >> 7, h = j & 127;
        const int srow = h + ((g == 0) ? 0 : (g + 1) * 128);
        const int kt = s >> 2, qq = s & 3;
        const float* pA = Wih1 + (size_t)srow * H + kt * 32 + qq * 4;
        Frag f = cvt44(*reinterpret_cast<const float4*>(pA),
                       *reinterpret_cast<const float4*>(pA + 16));
        w1s[(j << 4) + (s ^ (j & 7))] = f.u;
    }
    // ---- Stage heads pi-permuted (+ zero-fill rows 17-31): 512 granules ----
    {
        const int j = tid >> 4, s = tid & 15;
        const int kt = s >> 2, qq = s & 3;
        Frag f;
        if (j <= 16) {
            const float* base = (j < 16) ? (Wp + (size_t)j * H) : Wv;
            const float* pA = base + kt * 32 + qq * 4;
            f = cvt44(*reinterpret_cast<const float4*>(pA),
                      *reinterpret_cast<const float4*>(pA + 16));
        } else {
            f.u = make_uint4(0u, 0u, 0u, 0u);
        }
        wph[(j << 4) + (s ^ (j & 7))] = f.u;
    }
    // ---- Stage biases (igo-packed, bih+bhh pre-summed) ----
#pragma unroll
    for (int r = 0; r < 2; ++r) {
        const int t = tid + (r << 9);
        if (t < 384) {
            const int g = t >> 7, h = t & 127;
            const int srow = h + ((g == 0) ? 0 : (g + 1) * 128);
            b0s[t] = bih0[srow] + bhh0[srow];
        } else if (t < 768) {
            const int tt = t - 384;
            const int g = tt >> 7, h = tt & 127;
            const int srow = h + ((g == 0) ? 0 : (g + 1) * 128);
            b1s[tt] = bih1[srow] + bhh1[srow];
        }
    }

    __syncthreads();   // the ONLY barrier in the kernel

    const int swz = m & 7;
    Frag xb[2][2];
#pragma unroll
    for (int s2 = 0; s2 < 2; ++s2) {
        xb[s2][0] = cvt8(xr[s2][0]);
        xb[s2][1] = cvt8(xr[s2][1]);
    }

    // ===== Layer 0 (static unroll): packed h-words -> b1 frag components ====
    Frag b1[2][4];
#pragma unroll
    for (int nc = 0; nc < 8; ++nc) {
        f32x4 acc[3][2];
#pragma unroll
        for (int g = 0; g < 3; ++g) { acc[g][0] = vzero; acc[g][1] = vzero; }
#pragma unroll
        for (int g = 0; g < 3; ++g) {
            const int n = g * 128 + nc * 16 + m;
#pragma unroll
            for (int kt = 0; kt < 2; ++kt) {
                Frag a; a.u = w0s[(n << 3) + ((kt * 4 + q) ^ swz)];
#pragma unroll
                for (int s2 = 0; s2 < 2; ++s2)
                    acc[g][s2] = __builtin_amdgcn_mfma_f32_16x16x32_bf16(
                        a.v, xb[s2][kt].v, acc[g][s2], 0, 0, 0);
            }
        }
        const f32x4 bI = *reinterpret_cast<const f32x4*>(b0s +       nc * 16 + q * 4);
        const f32x4 bG = *reinterpret_cast<const f32x4*>(b0s + 128 + nc * 16 + q * 4);
        const f32x4 bO = *reinterpret_cast<const f32x4*>(b0s + 256 + nc * 16 + q * 4);
#pragma unroll
        for (int s2 = 0; s2 < 2; ++s2) {
            const float h0a = lstm_h(acc[0][s2][0] + bI[0], acc[1][s2][0] + bG[0], acc[2][s2][0] + bO[0]);
            const float h0b = lstm_h(acc[0][s2][1] + bI[1], acc[1][s2][1] + bG[1], acc[2][s2][1] + bO[1]);
            const float h1a = lstm_h(acc[0][s2][2] + bI[2], acc[1][s2][2] + bG[2], acc[2][s2][2] + bO[2]);
            const float h1b = lstm_h(acc[0][s2][3] + bI[3], acc[1][s2][3] + bG[3], acc[2][s2][3] + bO[3]);
            const unsigned wu0 = pk2(h0a, h0b);   // word 2*nc   (u=0)
            const unsigned wu1 = pk2(h1a, h1b);   // word 2*nc+1 (u=1)
            if ((nc & 1) == 0) { b1[s2][nc >> 1].u.x = wu0; b1[s2][nc >> 1].u.y = wu1; }
            else               { b1[s2][nc >> 1].u.z = wu0; b1[s2][nc >> 1].u.w = wu1; }
        }
    }

    // ===== Layer 1 + heads, ROLLED (8 iterations, ~2 KB of code) ============
    f32x4 ap[2], av[2];
    ap[0] = vzero; ap[1] = vzero; av[0] = vzero; av[1] = vzero;
    uint2 hold[2];
#pragma unroll 1
    for (int nc = 0; nc < 8; ++nc) {
        f32x4 acc[3][2];
#pragma unroll
        for (int g = 0; g < 3; ++g) { acc[g][0] = vzero; acc[g][1] = vzero; }
        const int nbase = nc * 16 + m;
#pragma unroll
        for (int kt = 0; kt < 4; ++kt) {
#pragma unroll
            for (int g = 0; g < 3; ++g) {
                Frag a; a.u = w1s[((g * 128 + nbase) << 4) + ((kt * 4 + q) ^ swz)];
#pragma unroll
                for (int s2 = 0; s2 < 2; ++s2)
                    acc[g][s2] = __builtin_amdgcn_mfma_f32_16x16x32_bf16(
                        a.v, b1[s2][kt].v, acc[g][s2], 0, 0, 0);
            }
        }
        const f32x4 bI = *reinterpret_cast<const f32x4*>(b1s +       nc * 16 + q * 4);
        const f32x4 bG = *reinterpret_cast<const f32x4*>(b1s + 128 + nc * 16 + q * 4);
        const f32x4 bO = *reinterpret_cast<const f32x4*>(b1s + 256 + nc * 16 + q * 4);
#pragma unroll
        for (int s2 = 0; s2 < 2; ++s2) {
            const float h0a = lstm_h(acc[0][s2][0] + bI[0], acc[1][s2][0] + bG[0], acc[2][s2][0] + bO[0]);
            const float h0b = lstm_h(acc[0][s2][1] + bI[1], acc[1][s2][1] + bG[1], acc[2][s2][1] + bO[1]);
            const float h1a = lstm_h(acc[0][s2][2] + bI[2], acc[1][s2][2] + bG[2], acc[2][s2][2] + bO[2]);
            const float h1b = lstm_h(acc[0][s2][3] + bI[3], acc[1][s2][3] + bG[3], acc[2][s2][3] + bO[3]);
            const unsigned wu0 = pk2(h0a, h0b);   // word 2*nc
            const unsigned wu1 = pk2(h1a, h1b);   // word 2*nc+1
            if ((nc & 1) == 0) {
                hold[s2].x = wu0; hold[s2].y = wu1;
            } else {
                // head B-frag for kt' = nc>>1 complete: {w[4kt'..4kt'+3]}
                Frag bh; bh.u = make_uint4(hold[s2].x, hold[s2].y, wu0, wu1);
                const int ktp = nc >> 1;
                Frag a0; a0.u = wph[( m       << 4) + ((ktp * 4 + q) ^ swz)];
                Frag a1; a1.u = wph[((16 + m) << 4) + ((ktp * 4 + q) ^ swz)]; // (16+m)&7==m&7
                ap[s2] = __builtin_amdgcn_mfma_f32_16x16x32_bf16(a0.v, bh.v, ap[s2], 0, 0, 0);
                av[s2] = __builtin_amdgcn_mfma_f32_16x16x32_bf16(a1.v, bh.v, av[s2], 0, 0, 0);
            }
        }
    }

    // ===== Epilogue: policy + value stores ==================================
#pragma unroll
    for (int s2 = 0; s2 < 2; ++s2) {
        const int row = rbase + s2 * 16 + m;
        // policy: D col = batch m, row = action q*4+r -> one dwordx4 per lane
        f32x4 po;
        po[0] = ap[s2][0] + bpr.x; po[1] = ap[s2][1] + bpr.y;
        po[2] = ap[s2][2] + bpr.z; po[3] = ap[s2][3] + bpr.w;
        *reinterpret_cast<f32x4*>(out + (size_t)row * NA + q * 4) = po;
        // value lives at tile1 in-tile row 0 -> q==0, reg 0
        if (q == 0) out[(size_t)BATCH * NA + row] = av[s2][0] + bvv;
    }
}

extern "C" void kernel_launch(void* const* d_in, const int* in_sizes, int n_in,
                              void* d_out, int out_size, void* d_ws, size_t ws_size,
                              hipStream_t stream) {
    // setup_inputs order: x, Wih0, Whh0, bih0, bhh0, Wih1, Whh1, bih1, bhh1, Wp, bp, Wv, bv
    // Whh0 (idx 2) / Whh1 (idx 6) dead (h_prev = 0); f-gate dead (c_prev = 0).
    lstm_fused<<<dim3(NBLK), dim3(TPB), 0, stream>>>(
        (const float*)d_in[0], (const float*)d_in[1],
        (const float*)d_in[3], (const float*)d_in[4],
        (const float*)d_in[5], (const float*)d_in[7],
        (const float*)d_in[8], (const float*)d_in[9],
        (const float*)d_in[10], (const float*)d_in[11],
        (const float*)d_in[12], (float*)d_out);
}